// Round 2
// baseline (194.648 us; speedup 1.0000x reference)
//
#include <hip/hip_runtime.h>
#include <stdint.h>

// out[n,k,y,x] = sum_c grid[n,k,c,y/16,x/16] * guidemap[n,c,y,x]
// N=2, K=C=32, H=W=1024, block grid 64x64, block size 16x16.
//
// Persistent 2-phase pipelined version:
//  - 512 WGs (2/CU), each owns 16 consecutive tiles (one quarter by-row).
//  - XCD-grouped ranges: WG w -> range (w&7)*64 + (w>>3); dispatch round-robin
//    puts each XCD on a contiguous 1024-tile span -> all 128B lines L2-local.
//  - global_load_lds staging (16B guide, 4B matrix) double-buffered; counted
//    vmcnt (never 0 mid-loop) + raw s_barrier keeps prefetch in flight.

namespace {
constexpr int NIMG = 2, K = 32, C = 32;
constexpr int HB = 64, WB = 64, F1 = 16, F2 = 16;
constexpr int H = 1024, W = 1024;
constexpr int HW = H * W;
constexpr int TILES_TOTAL = NIMG * HB * WB;  // 8192
constexpr int NWG = 512;
constexpr int TPW = TILES_TOTAL / NWG;       // 16 tiles per WG
constexpr int GUIDE_F = C * F1 * F2;         // 8192 floats = 32 KB
constexpr int MAT_F = K * C;                 // 1024 floats = 4 KB
constexpr int BUF_F = GUIDE_F + MAT_F;       // 9216 floats = 36 KB
}

__device__ __forceinline__ void gl_lds16(const float* src, float* dst) {
    __builtin_amdgcn_global_load_lds(
        (const __attribute__((address_space(1))) void*)src,
        (__attribute__((address_space(3))) void*)dst, 16, 0, 0);
}
__device__ __forceinline__ void gl_lds4(const float* src, float* dst) {
    __builtin_amdgcn_global_load_lds(
        (const __attribute__((address_space(1))) void*)src,
        (__attribute__((address_space(3))) void*)dst, 4, 0, 0);
}

// Stage one tile (by,bx) into buf: guide [c][64 float4 chunks] + matrix [c][k].
__device__ __forceinline__ void stage_tile(const float* __restrict__ gm_n,
                                           const float* __restrict__ grd_n,
                                           float* buf, int by, int bx, int t) {
    const float* gbase = gm_n + (by * F1) * W + bx * F2;
#pragma unroll
    for (int i = 0; i < 4; ++i) {
        const int e = t + 512 * i;       // float4 index 0..2047
        const int c = e >> 6;
        const int l = e & 63;
        const int r = l >> 2;            // row 0..15
        const int col = (l & 3) << 2;    // col 0,4,8,12
        gl_lds16(gbase + (size_t)c * HW + r * W + col, buf + 4 * e);
    }
    const float* mb = grd_n + by * WB + bx;
#pragma unroll
    for (int i = 0; i < 2; ++i) {
        const int e = t + 512 * i;       // e = c*32 + k
        const int k = e & 31;
        const int c = e >> 5;
        gl_lds4(mb + (size_t)(k * C + c) * (HB * WB), buf + GUIDE_F + e);
    }
}

__device__ __forceinline__ void compute_store(const float* buf,
                                              float* __restrict__ out_n,
                                              int by, int bx, int kg, int l) {
    const float4* G = (const float4*)buf;               // [C][64]
    const float4* M = (const float4*)(buf + GUIDE_F);   // [C][8]
    float acc[4][4] = {};
#pragma unroll
    for (int c = 0; c < C; ++c) {
        const float4 g = G[c * 64 + l];   // lanes stride 16B: conflict-free
        const float4 m = M[c * 8 + kg];   // wave-uniform broadcast
        const float gv[4] = {g.x, g.y, g.z, g.w};
        const float mv[4] = {m.x, m.y, m.z, m.w};
#pragma unroll
        for (int dk = 0; dk < 4; ++dk)
#pragma unroll
            for (int p = 0; p < 4; ++p) acc[dk][p] += mv[dk] * gv[p];
    }
    const int r = l >> 2;
    const int col = (l & 3) << 2;
    float* ob = out_n + (size_t)(kg * 4) * HW + (by * F1 + r) * W + bx * F2 + col;
#pragma unroll
    for (int dk = 0; dk < 4; ++dk) {
        const float4 v = {acc[dk][0], acc[dk][1], acc[dk][2], acc[dk][3]};
        *reinterpret_cast<float4*>(ob + (size_t)dk * HW) = v;
    }
}

__global__ __launch_bounds__(512, 2) void gridup_kernel(
    const float* __restrict__ grd,   // [N][K][C][HB][WB]
    const float* __restrict__ gm,    // [N][C][H][W]
    float* __restrict__ out)         // [N][K][H][W]
{
    __shared__ float lds[2][BUF_F];  // 72 KB total -> 2 WG/CU

    const int wg = blockIdx.x;                     // 0..511
    const int range = (wg & 7) * 64 + (wg >> 3);   // XCD-contiguous ranges
    const int tile0 = range * TPW;
    const int t = threadIdx.x;
    const int kg = t >> 6;   // wave id: 4 k's
    const int l = t & 63;    // pixel chunk: 4 px

    // All 16 tiles of a range share n and by (ranges don't cross rows/images).
    const int n = tile0 >> 12;
    const int rem = tile0 & 4095;
    const int by = rem >> 6;
    const int bx0 = rem & 63;

    const float* gm_n = gm + (size_t)n * C * HW;
    const float* grd_n = grd + (size_t)n * (K * C * HB * WB);
    float* out_n = out + (size_t)n * K * HW;

    stage_tile(gm_n, grd_n, lds[0], by, bx0, t);

    int cur = 0;
#pragma unroll 1
    for (int i = 0; i < TPW; ++i) {
        if (i + 1 < TPW) {
            stage_tile(gm_n, grd_n, lds[cur ^ 1], by, bx0 + i + 1, t);
            // Outstanding: stage(i)=6 [+ 4 stores of i-1] + stage(i+1)=6.
            // Drain stage(i) only; keep stage(i+1) in flight.
            if (i == 0) asm volatile("s_waitcnt vmcnt(6)" ::: "memory");
            else        asm volatile("s_waitcnt vmcnt(10)" ::: "memory");
        } else {
            // Last tile: outstanding = stage(i)=6 + 4 stores -> drain stage.
            asm volatile("s_waitcnt vmcnt(4)" ::: "memory");
        }
        __builtin_amdgcn_s_barrier();      // all waves see buf[cur] complete
        asm volatile("" ::: "memory");

        compute_store(lds[cur], out_n, by, bx0 + i, kg, l);

        // All ds_reads were consumed (lgkmcnt drained by compiler) before
        // stores; barrier guards buf[cur] against next iteration's stage.
        asm volatile("s_waitcnt lgkmcnt(0)" ::: "memory");
        __builtin_amdgcn_s_barrier();
        asm volatile("" ::: "memory");
        cur ^= 1;
    }
}

extern "C" void kernel_launch(void* const* d_in, const int* in_sizes, int n_in,
                              void* d_out, int out_size, void* d_ws, size_t ws_size,
                              hipStream_t stream) {
    const float* grd = (const float*)d_in[0];   // grid:     2*32*32*64*64
    const float* gm  = (const float*)d_in[1];   // guidemap: 2*32*1024*1024
    float* out = (float*)d_out;                 // 2*32*1024*1024 fp32

    gridup_kernel<<<NWG, 512, 0, stream>>>(grd, gm, out);
}

// Round 3
// 165.172 us; speedup vs baseline: 1.1785x; 1.1785x over previous
//
#include <hip/hip_runtime.h>

// out[n,k,y,x] = sum_c grid[n,k,c,y/16,x/16] * guidemap[n,c,y,x]
// N=2, K=C=32, H=W=1024, 64x64 tiles of 16x16 px.
//
// R3: barrier-free streaming design.
//  - Thread = 2 px, all 32 k. acc[32][2] in VGPRs.
//  - Guide: direct global->reg float2 loads, 4-deep channel prefetch ring.
//  - Matrix: 4 KB/tile staged once to LDS (gl_lds4), read as wave-uniform
//    ds_read_b128 broadcast. One __syncthreads per WG lifetime; hot loop
//    has zero barriers.
//  - WG = 256 thr = 2 adjacent-bx tiles (shares 128B lines within the WG);
//    XCD-contiguous tile spans for L2 locality.

namespace {
constexpr int K = 32, C = 32;
constexpr int W = 1024;
constexpr int HW = 1024 * 1024;
constexpr size_t GRDN = (size_t)K * C * 64 * 64;  // 4194304 floats per image
}

__device__ __forceinline__ void gl_lds4(const float* src, float* dst) {
    __builtin_amdgcn_global_load_lds(
        (const __attribute__((address_space(1))) void*)src,
        (__attribute__((address_space(3))) void*)dst, 4, 0, 0);
}

__global__ __launch_bounds__(256, 4) void gridup_kernel(
    const float* __restrict__ grd,   // [N][K][C][64][64]
    const float* __restrict__ gm,    // [N][C][1024][1024]
    float* __restrict__ out)         // [N][K][1024][1024]
{
    __shared__ float sM[2][C][K];    // two tiles' matrices, 8 KB

    int wg = blockIdx.x;
    wg = (wg & 7) * 512 + (wg >> 3);   // XCD x owns tiles [x*1024,(x+1)*1024)
    const int t = threadIdx.x;
    const int g0 = wg * 2;             // first of the WG's two tiles

    // ---- stage both matrices into LDS: linear LDS order e=[tile][c][k],
    //      per-lane scattered 4B global gathers (L2-deduped across bx).
    #pragma unroll
    for (int i = 0; i < 8; ++i) {
        const int e  = i * 256 + t;    // 0..2047
        const int t2 = e >> 10;
        const int c  = (e >> 5) & 31;
        const int k  = e & 31;
        const int gt2 = g0 + t2;
        const int n2  = gt2 >> 12;
        const int rr2 = gt2 & 4095;
        const int by2 = rr2 >> 6;
        const int bx2 = rr2 & 63;
        gl_lds4(grd + (size_t)n2 * GRDN + (size_t)(k * 32 + c) * 4096 + by2 * 64 + bx2,
                &sM[0][0][0] + e);
    }
    __syncthreads();   // only barrier in the kernel

    const int tl = t >> 7;             // which of the WG's two tiles
    const int gt = g0 + tl;
    const int n  = gt >> 12;
    const int rr = gt & 4095;
    const int by = rr >> 6;
    const int bx = rr & 63;

    const float* M = &sM[tl][0][0];
    const int p   = (t & 127) * 2;     // px within tile: 0..254 even
    const int row = p >> 4;
    const int col = p & 15;
    const size_t pix = (size_t)(by * 16 + row) * W + bx * 16 + col;
    const float* gb = gm + (size_t)n * C * HW + pix;
    float*       ob = out + (size_t)n * K * HW + pix;

    float acc[32][2] = {};
    float2 gc[4], gn[4];
    #pragma unroll
    for (int j = 0; j < 4; ++j)
        gc[j] = *reinterpret_cast<const float2*>(gb + (size_t)j * HW);

    for (int cb = 0; cb < 8; ++cb) {
        if (cb < 7) {                  // wave-uniform branch
            #pragma unroll
            for (int j = 0; j < 4; ++j)
                gn[j] = *reinterpret_cast<const float2*>(
                    gb + (size_t)((cb + 1) * 4 + j) * HW);
        }
        #pragma unroll
        for (int j = 0; j < 4; ++j) {
            const int c = cb * 4 + j;
            const float2 g = gc[j];
            #pragma unroll
            for (int kq = 0; kq < 8; ++kq) {
                // wave-uniform 16B LDS read: broadcast, conflict-free
                const float4 m = *reinterpret_cast<const float4*>(M + c * 32 + kq * 4);
                acc[kq * 4 + 0][0] += m.x * g.x;  acc[kq * 4 + 0][1] += m.x * g.y;
                acc[kq * 4 + 1][0] += m.y * g.x;  acc[kq * 4 + 1][1] += m.y * g.y;
                acc[kq * 4 + 2][0] += m.z * g.x;  acc[kq * 4 + 2][1] += m.z * g.y;
                acc[kq * 4 + 3][0] += m.w * g.x;  acc[kq * 4 + 3][1] += m.w * g.y;
            }
        }
        if (cb < 7) {
            #pragma unroll
            for (int j = 0; j < 4; ++j) gc[j] = gn[j];
        }
    }

    #pragma unroll
    for (int k = 0; k < 32; ++k) {
        const float2 v = {acc[k][0], acc[k][1]};
        *reinterpret_cast<float2*>(ob + (size_t)k * HW) = v;
    }
}

extern "C" void kernel_launch(void* const* d_in, const int* in_sizes, int n_in,
                              void* d_out, int out_size, void* d_ws, size_t ws_size,
                              hipStream_t stream) {
    const float* grd = (const float*)d_in[0];   // grid:     2*32*32*64*64
    const float* gm  = (const float*)d_in[1];   // guidemap: 2*32*1024*1024
    float* out = (float*)d_out;                 // 2*32*1024*1024 fp32

    gridup_kernel<<<4096, 256, 0, stream>>>(grd, gm, out);
}